// Round 10
// baseline (212.012 us; speedup 1.0000x reference)
//
#include <hip/hip_runtime.h>
#include <cstdint>

// B=4, S=2048, D_IN=D_OUT=1024; softmax scale = 1/sqrt(1024) = 0.03125
// exp without max-subtraction is safe (|scores| ~< 3); L = rowsum via atomics;
// 1/L folded into PV epilogue.
//
// R10 = R9 (best measured, 211.9us) + pv XCD panel-clustering:
// pv grid flattened to 512 linear blocks; HW XCD = lin%8, and the remap
// puts all 8 bx of one (by,bz) panel on the SAME XCD (they read the
// identical P panel -> L2 reuse instead of 8x refetch across XCDs), with
// panels round-robin across XCDs in LPT order (by=15 first; per-XCD
// k-step load 72/64, balanced). Index-only change vs R9.
// GEMM structure: 128x128 tile, BK=64, 8-chunk XOR LDS swizzle (0 conflicts
// measured), global_load_lds staging, T1 bijective XCD swizzle (qkv, scores).
// Session ledger: R2 256^2 8-phase = 84us qkv (reverted); R5 col-64 split =
// +7us (reverted); R7 sv-merge = neutral; R8 split-K pv = +9us (reverted).
// Plateau {R4 217.0, R7 218.0, R9 211.9}; qkv at m97-structure ceiling
// (865 TF @ 6 rounds/CU); ~47us/rep is harness-fixed (reset dispatches).

typedef __attribute__((ext_vector_type(8))) __bf16 bf16x8;
typedef __attribute__((ext_vector_type(4))) float f32x4;

#define BK 64

__device__ __forceinline__ unsigned short f2bf(float f) {
  union { float f; unsigned u; } v; v.f = f;
  unsigned r = v.u + 0x7fffu + ((v.u >> 16) & 1u);  // RNE
  return (unsigned short)(r >> 16);
}

__device__ __forceinline__ void gload_lds16(const void* g, void* l) {
  __builtin_amdgcn_global_load_lds(
      (const __attribute__((address_space(1))) void*)g,
      (__attribute__((address_space(3))) void*)l, 16, 0, 0);
}

// ------------- fused fp32->bf16 conversion (X + weights) + L zero ----------
__global__ __launch_bounds__(256)
void cvt_all(const float* __restrict__ X, const float* __restrict__ Wq,
             const float* __restrict__ Wk, const float* __restrict__ Wv,
             unsigned short* __restrict__ Xbf, unsigned short* __restrict__ Wall,
             float* __restrict__ L) {
  const int bid = blockIdx.x;
  if (bid >= 11264) {  // 4 blocks zero L[4][2048]
    float4* p = (float4*)(L + (size_t)(bid - 11264) * 2048);
    p[threadIdx.x] = (float4){0.f, 0.f, 0.f, 0.f};
    p[threadIdx.x + 256] = (float4){0.f, 0.f, 0.f, 0.f};
    return;
  }
  const float* src;
  unsigned short* dst;
  int i;
  if (bid < 8192) {
    src = X; dst = Xbf; i = bid * 256 + threadIdx.x;
  } else {
    const int m = bid - 8192;
    const int sel = m >> 10;
    src = (sel == 0) ? Wq : (sel == 1) ? Wk : Wv;
    dst = Wall + (size_t)sel * 1048576;
    i = (m & 1023) * 256 + threadIdx.x;
  }
  float4 v = ((const float4*)src)[i];
  ushort4 o;
  o.x = f2bf(v.x); o.y = f2bf(v.y); o.z = f2bf(v.z); o.w = f2bf(v.w);
  ((ushort4*)dst)[i] = o;
}

// -------------------- fused QKV GEMM (128x128, BK=64) --------------------
// A = Xbf [8192][1024], B = Wall [3072][1024]
// grid (24, 64): bx<8 -> Q; bx<16 -> K; else V transposed into Vt[b][e][s].
__global__ __launch_bounds__(256, 3)
void gemm_qkv(const unsigned short* __restrict__ A,
              const unsigned short* __restrict__ Bm,
              unsigned short* __restrict__ Qb,
              unsigned short* __restrict__ Kb,
              unsigned short* __restrict__ Vt)
{
  // T1: bijective XCD swizzle (1536 % 8 == 0). Dispatch order is x-fastest,
  // so lin%8 = XCD id; give each XCD 192 consecutive tiles = 8 full by-rows
  // (A-panel working set 8*256KB = 2MB < 4MB XCD L2).
  const int lin = blockIdx.y * 24 + blockIdx.x;
  const int swz = (lin & 7) * 192 + (lin >> 3);
  const int bx = swz % 24, by = swz / 24;

  __shared__ __align__(16) unsigned short As[128 * BK];  // 16 KB
  __shared__ __align__(16) unsigned short Bs[128 * BK];  // 16 KB

  const int tid = threadIdx.x;
  const int wave = tid >> 6, lane = tid & 63;
  const int wr = wave >> 1, wc = wave & 1;
  const int quad = lane >> 4, l16 = lane & 15;

  const unsigned rsub = wave * 8 + (lane >> 3);
  const unsigned csb = (unsigned)(((lane & 7) ^ ((lane >> 3) & 7)) * 16);  // byte off in row

  // per-lane 32-bit byte offsets; uniform bases stay in SGPRs
  unsigned offA[4], offB[4];
  #pragma unroll
  for (int s = 0; s < 4; ++s) {
    offA[s] = ((unsigned)(by * 128 + s * 32 + rsub) * 1024u) * 2u + csb;
    offB[s] = ((unsigned)(bx * 128 + s * 32 + rsub) * 1024u) * 2u + csb;
  }
  const char* Abase = (const char*)A;
  const char* Bbase = (const char*)Bm;

  f32x4 acc[4][4];
  #pragma unroll
  for (int i = 0; i < 4; ++i)
    #pragma unroll
    for (int j = 0; j < 4; ++j)
      acc[i][j] = (f32x4){0.f, 0.f, 0.f, 0.f};

  const int pq = (quad ^ (l16 & 7)) * 8;
  const int aOff = (wr * 64 + l16) * BK + pq;
  const int bOff = (wc * 64 + l16) * BK + pq;

  for (int k0 = 0; k0 < 1024; k0 += BK) {
    const unsigned kb = (unsigned)k0 * 2u;
    #pragma unroll
    for (int s = 0; s < 4; ++s) {
      gload_lds16(Abase + kb + offA[s], As + s * 2048 + wave * 512);
      gload_lds16(Bbase + kb + offB[s], Bs + s * 2048 + wave * 512);
    }
    __syncthreads();
    #pragma unroll
    for (int h = 0; h < 2; ++h) {
      const int hx = h * 32;
      bf16x8 af[4], bfr[4];
      #pragma unroll
      for (int i = 0; i < 4; ++i)
        af[i] = *(const bf16x8*)(As + ((aOff + i * 16 * BK) ^ hx));
      #pragma unroll
      for (int j = 0; j < 4; ++j)
        bfr[j] = *(const bf16x8*)(Bs + ((bOff + j * 16 * BK) ^ hx));
      #pragma unroll
      for (int i = 0; i < 4; ++i)
        #pragma unroll
        for (int j = 0; j < 4; ++j)
          acc[i][j] = __builtin_amdgcn_mfma_f32_16x16x32_bf16(af[i], bfr[j], acc[i][j], 0, 0, 0);
    }
    __syncthreads();
  }

  const int row0 = by * 128 + wr * 64 + quad * 4;
  const int col0 = bx * 128 + wc * 64 + l16;
  if (bx < 16) {
    unsigned short* C = (bx < 8) ? Qb : Kb;
    const int col = (bx < 8) ? col0 : col0 - 1024;
    #pragma unroll
    for (int i = 0; i < 4; ++i)
      #pragma unroll
      for (int r = 0; r < 4; ++r) {
        const size_t rr = (size_t)(row0 + i * 16 + r) * 1024;
        #pragma unroll
        for (int j = 0; j < 4; ++j)
          C[rr + col + j * 16] = f2bf(acc[i][j][r]);
      }
  } else {
    const int b = row0 >> 11;
    const int s0 = row0 & 2047;
    unsigned short* Vb = Vt + (size_t)b * 2097152;
    #pragma unroll
    for (int j = 0; j < 4; ++j) {
      const size_t ee = (size_t)(col0 - 2048 + j * 16) * 2048;
      #pragma unroll
      for (int i = 0; i < 4; ++i) {
        ushort4 o;
        o.x = f2bf(acc[i][j][0]); o.y = f2bf(acc[i][j][1]);
        o.z = f2bf(acc[i][j][2]); o.w = f2bf(acc[i][j][3]);
        *(ushort4*)(Vb + ee + s0 + i * 16) = o;
      }
    }
  }
}

// -------------------- scores (128x128, BK=64) + exp + rowsum ----------------
// S'[b] = exp(scale*Q@K^T) causal-masked, bf16; L[b][q] += partial rowsums.
// Triangular-packed grid.x (136 tiles), z = batch.
__global__ __launch_bounds__(256, 3)
void gemm_scores(const unsigned short* __restrict__ Q,
                 const unsigned short* __restrict__ Km,
                 unsigned short* __restrict__ S,
                 float* __restrict__ L)
{
  // T1: bijective XCD swizzle over 136 = 8*17 triangular tiles; consecutive
  // t' share by -> Q-panel L2 reuse within an XCD.
  const int t0i = blockIdx.x;
  const int t = (t0i & 7) * 17 + (t0i >> 3);
  const int bz = blockIdx.z;
  int by = (int)((sqrtf(8.f * t + 1.f) - 1.f) * 0.5f);
  while ((by + 1) * (by + 2) / 2 <= t) ++by;
  while (by * (by + 1) / 2 > t) --by;
  const int bx = t - by * (by + 1) / 2;

  __shared__ __align__(16) unsigned short As2[128 * BK];
  __shared__ __align__(16) unsigned short Bs2[128 * BK];

  const int tid = threadIdx.x;
  const int wave = tid >> 6, lane = tid & 63;
  const int wr = wave >> 1, wc = wave & 1;
  const int quad = lane >> 4, l16 = lane & 15;

  const unsigned rsub = wave * 8 + (lane >> 3);
  const unsigned csb = (unsigned)(((lane & 7) ^ ((lane >> 3) & 7)) * 16);

  unsigned offA[4], offB[4];
  #pragma unroll
  for (int s = 0; s < 4; ++s) {
    offA[s] = ((unsigned)(by * 128 + s * 32 + rsub) * 1024u) * 2u + csb;
    offB[s] = ((unsigned)(bx * 128 + s * 32 + rsub) * 1024u) * 2u + csb;
  }
  const char* Abase = (const char*)(Q + (size_t)bz * 2097152);
  const char* Bbase = (const char*)(Km + (size_t)bz * 2097152);

  f32x4 acc[4][4];
  #pragma unroll
  for (int i = 0; i < 4; ++i)
    #pragma unroll
    for (int j = 0; j < 4; ++j)
      acc[i][j] = (f32x4){0.f, 0.f, 0.f, 0.f};

  const int pq = (quad ^ (l16 & 7)) * 8;
  const int aOff = (wr * 64 + l16) * BK + pq;
  const int bOff = (wc * 64 + l16) * BK + pq;

  for (int k0 = 0; k0 < 1024; k0 += BK) {
    const unsigned kb = (unsigned)k0 * 2u;
    #pragma unroll
    for (int s = 0; s < 4; ++s) {
      gload_lds16(Abase + kb + offA[s], As2 + s * 2048 + wave * 512);
      gload_lds16(Bbase + kb + offB[s], Bs2 + s * 2048 + wave * 512);
    }
    __syncthreads();
    #pragma unroll
    for (int h = 0; h < 2; ++h) {
      const int hx = h * 32;
      bf16x8 af[4], bfr[4];
      #pragma unroll
      for (int i = 0; i < 4; ++i)
        af[i] = *(const bf16x8*)(As2 + ((aOff + i * 16 * BK) ^ hx));
      #pragma unroll
      for (int j = 0; j < 4; ++j)
        bfr[j] = *(const bf16x8*)(Bs2 + ((bOff + j * 16 * BK) ^ hx));
      #pragma unroll
      for (int i = 0; i < 4; ++i)
        #pragma unroll
        for (int j = 0; j < 4; ++j)
          acc[i][j] = __builtin_amdgcn_mfma_f32_16x16x32_bf16(af[i], bfr[j], acc[i][j], 0, 0, 0);
    }
    __syncthreads();
  }

  const int row0 = by * 128 + wr * 64 + quad * 4;
  const int col0 = bx * 128 + wc * 64 + l16;
  float* Lb = L + (size_t)bz * 2048;
  unsigned short* C = S + (size_t)bz * 4194304;

  #pragma unroll
  for (int i = 0; i < 4; ++i)
    #pragma unroll
    for (int r = 0; r < 4; ++r) {
      const int grow = row0 + i * 16 + r;
      float ps = 0.f;
      #pragma unroll
      for (int j = 0; j < 4; ++j) {
        const int gcol = col0 + j * 16;
        float e = (gcol <= grow) ? __expf(acc[i][j][r] * 0.03125f) : 0.f;
        acc[i][j][r] = e;
        ps += e;
      }
      #pragma unroll
      for (int m = 8; m > 0; m >>= 1)
        ps += __shfl_xor(ps, m);
      if (l16 == 0) atomicAdd(&Lb[grow], ps);
      const size_t rr = (size_t)grow * 2048;
      #pragma unroll
      for (int j = 0; j < 4; ++j)
        C[rr + col0 + j * 16] = f2bf(acc[i][j][r]);
    }
}

// -------------------- PV (128x128, BK=64) with 1/L normalization ------------
// Out[b] = (P'[b] @ Vt[b]^T) / L; grid 512 linear; kmax = (by+1)*128.
// XCD panel-clustering: HW XCD = lin%8. Decode puts all 8 bx of panel
// r = (lin>>6)*8 + (lin&7) on XCD r%8 (they read the identical P panel ->
// L2 reuse); panels round-robin across XCDs in LPT order (by = 15 - (r>>2),
// bz = r&3): by=15 panels dispatch first, per-XCD k-load 72/64 balanced.
__global__ __launch_bounds__(256, 3)
void gemm_pv(const unsigned short* __restrict__ P,
             const unsigned short* __restrict__ Vt,
             float* __restrict__ Out,
             const float* __restrict__ L)
{
  const int lin = blockIdx.x;                 // 0..511
  const int bx = (lin >> 3) & 7;
  const int r = ((lin >> 6) << 3) | (lin & 7);  // panel rank, XCD = r%8
  const int by = 15 - (r >> 2);
  const int bz = r & 3;

  __shared__ __align__(16) unsigned short As2[128 * BK];
  __shared__ __align__(16) unsigned short Bs2[128 * BK];

  const int tid = threadIdx.x;
  const int wave = tid >> 6, lane = tid & 63;
  const int wr = wave >> 1, wc = wave & 1;
  const int quad = lane >> 4, l16 = lane & 15;

  const unsigned rsub = wave * 8 + (lane >> 3);
  const unsigned csb = (unsigned)(((lane & 7) ^ ((lane >> 3) & 7)) * 16);

  unsigned offA[4], offB[4];
  #pragma unroll
  for (int s = 0; s < 4; ++s) {
    offA[s] = ((unsigned)(by * 128 + s * 32 + rsub) * 2048u) * 2u + csb;
    offB[s] = ((unsigned)(bx * 128 + s * 32 + rsub) * 2048u) * 2u + csb;
  }
  const char* Abase = (const char*)(P + (size_t)bz * 4194304);
  const char* Bbase = (const char*)(Vt + (size_t)bz * 2097152);

  f32x4 acc[4][4];
  #pragma unroll
  for (int i = 0; i < 4; ++i)
    #pragma unroll
    for (int j = 0; j < 4; ++j)
      acc[i][j] = (f32x4){0.f, 0.f, 0.f, 0.f};

  const int kmax = (by + 1) * 128;  // causal truncation, multiple of BK

  const int pq = (quad ^ (l16 & 7)) * 8;
  const int aOff = (wr * 64 + l16) * BK + pq;
  const int bOff = (wc * 64 + l16) * BK + pq;

  for (int k0 = 0; k0 < kmax; k0 += BK) {
    const unsigned kb = (unsigned)k0 * 2u;
    #pragma unroll
    for (int s = 0; s < 4; ++s) {
      gload_lds16(Abase + kb + offA[s], As2 + s * 2048 + wave * 512);
      gload_lds16(Bbase + kb + offB[s], Bs2 + s * 2048 + wave * 512);
    }
    __syncthreads();
    #pragma unroll
    for (int h = 0; h < 2; ++h) {
      const int hx = h * 32;
      bf16x8 af[4], bfr[4];
      #pragma unroll
      for (int i = 0; i < 4; ++i)
        af[i] = *(const bf16x8*)(As2 + ((aOff + i * 16 * BK) ^ hx));
      #pragma unroll
      for (int j = 0; j < 4; ++j)
        bfr[j] = *(const bf16x8*)(Bs2 + ((bOff + j * 16 * BK) ^ hx));
      #pragma unroll
      for (int i = 0; i < 4; ++i)
        #pragma unroll
        for (int j = 0; j < 4; ++j)
          acc[i][j] = __builtin_amdgcn_mfma_f32_16x16x32_bf16(af[i], bfr[j], acc[i][j], 0, 0, 0);
    }
    __syncthreads();
  }

  const int row0 = by * 128 + wr * 64 + quad * 4;
  const int col0 = bx * 128 + wc * 64 + l16;
  float* C = Out + (size_t)bz * 2097152;
  const float* Lb = L + (size_t)bz * 2048;
  #pragma unroll
  for (int i = 0; i < 4; ++i)
    #pragma unroll
    for (int r2 = 0; r2 < 4; ++r2) {
      const int grow = row0 + i * 16 + r2;
      const float inv = 1.0f / Lb[grow];
      const size_t rr = (size_t)grow * 1024;
      #pragma unroll
      for (int j = 0; j < 4; ++j)
        C[rr + col0 + j * 16] = acc[i][j][r2] * inv;
    }
}

// -------------------- launch --------------------
extern "C" void kernel_launch(void* const* d_in, const int* in_sizes, int n_in,
                              void* d_out, int out_size, void* d_ws, size_t ws_size,
                              hipStream_t stream) {
  const float* X  = (const float*)d_in[0];
  const float* Wq = (const float*)d_in[1];
  const float* Wk = (const float*)d_in[2];
  const float* Wv = (const float*)d_in[3];
  float* Out = (float*)d_out;

  char* ws = (char*)d_ws;
  unsigned short* Xbf  = (unsigned short*)(ws);              // [8192][1024]    16 MiB
  unsigned short* Wall = (unsigned short*)(ws + 16777216);   // [3072][1024]     6 MiB
  unsigned short* Qbf  = (unsigned short*)(ws + 23068672);   // [8192][1024]    16 MiB
  unsigned short* Kbf  = (unsigned short*)(ws + 39845888);   // [8192][1024]    16 MiB
  unsigned short* Vt   = (unsigned short*)(ws + 56623104);   // [4][1024][2048] 16 MiB
  unsigned short* Sbf  = (unsigned short*)(ws + 73400320);   // [4][2048][2048] 32 MiB
  float*          Lbuf = (float*)(ws + 106954752);           // [4][2048]       32 KiB

  cvt_all<<<11268, 256, 0, stream>>>(X, Wq, Wk, Wv, Xbf, Wall, Lbuf);

  gemm_qkv<<<dim3(24, 64), 256, 0, stream>>>(Xbf, Wall, Qbf, Kbf, Vt);

  gemm_scores<<<dim3(136, 1, 4), 256, 0, stream>>>(Qbf, Kbf, Sbf, Lbuf);

  gemm_pv<<<512, 256, 0, stream>>>(Sbf, Vt, Out, Lbuf);
}

// Round 13
// 210.312 us; speedup vs baseline: 1.0081x; 1.0081x over previous
//
#include <hip/hip_runtime.h>
#include <cstdint>

// B=4, S=2048, D_IN=D_OUT=1024; softmax scale = 1/sqrt(1024) = 0.03125
// exp without max-subtraction is safe (|scores| ~< 3); L = rowsum via atomics;
// 1/L folded into PV epilogue.
//
// R13 = byte-identical resubmission of R10 (best measured, 212.0us; R9 twin
// config 211.9us). R12 was an infra failure (container failed twice) -- the
// kernel never ran. R11's cooperative-kernel fusion RAN but produced garbage
// (absmax 2.19/468): grid.sync()+threadfence did not provide cross-phase
// visibility for the global_load_lds read path across non-coherent XCD L2s
// (or occupancy fell below the cooperative contract). Line abandoned.
// Structure: 128x128 tile, BK=64, 8-chunk XOR LDS swizzle (0 conflicts
// measured), global_load_lds staging, T1 bijective XCD swizzle (qkv, scores),
// pv XCD panel-clustering + LPT (neutral but harmless).
// Session ledger: R2 256^2 8-phase = 84us qkv (reverted); R5 col-64 split =
// +7us (reverted); R7 sv-merge = neutral; R8 split-K pv = +9us (reverted);
// R11 cooperative fusion = incorrect (reverted). Plateau {R9 211.9,
// R10 212.0}; qkv at m97-structure ceiling (865 TF @ 6 rounds/CU, MfmaUtil
// 36%, FETCH at L2-ideal); residual ~45-60us = harness-fixed per-rep work +
// 3 launch gaps.

typedef __attribute__((ext_vector_type(8))) __bf16 bf16x8;
typedef __attribute__((ext_vector_type(4))) float f32x4;

#define BK 64

__device__ __forceinline__ unsigned short f2bf(float f) {
  union { float f; unsigned u; } v; v.f = f;
  unsigned r = v.u + 0x7fffu + ((v.u >> 16) & 1u);  // RNE
  return (unsigned short)(r >> 16);
}

__device__ __forceinline__ void gload_lds16(const void* g, void* l) {
  __builtin_amdgcn_global_load_lds(
      (const __attribute__((address_space(1))) void*)g,
      (__attribute__((address_space(3))) void*)l, 16, 0, 0);
}

// ------------- fused fp32->bf16 conversion (X + weights) + L zero ----------
__global__ __launch_bounds__(256)
void cvt_all(const float* __restrict__ X, const float* __restrict__ Wq,
             const float* __restrict__ Wk, const float* __restrict__ Wv,
             unsigned short* __restrict__ Xbf, unsigned short* __restrict__ Wall,
             float* __restrict__ L) {
  const int bid = blockIdx.x;
  if (bid >= 11264) {  // 4 blocks zero L[4][2048]
    float4* p = (float4*)(L + (size_t)(bid - 11264) * 2048);
    p[threadIdx.x] = (float4){0.f, 0.f, 0.f, 0.f};
    p[threadIdx.x + 256] = (float4){0.f, 0.f, 0.f, 0.f};
    return;
  }
  const float* src;
  unsigned short* dst;
  int i;
  if (bid < 8192) {
    src = X; dst = Xbf; i = bid * 256 + threadIdx.x;
  } else {
    const int m = bid - 8192;
    const int sel = m >> 10;
    src = (sel == 0) ? Wq : (sel == 1) ? Wk : Wv;
    dst = Wall + (size_t)sel * 1048576;
    i = (m & 1023) * 256 + threadIdx.x;
  }
  float4 v = ((const float4*)src)[i];
  ushort4 o;
  o.x = f2bf(v.x); o.y = f2bf(v.y); o.z = f2bf(v.z); o.w = f2bf(v.w);
  ((ushort4*)dst)[i] = o;
}

// -------------------- fused QKV GEMM (128x128, BK=64) --------------------
// A = Xbf [8192][1024], B = Wall [3072][1024]
// grid (24, 64): bx<8 -> Q; bx<16 -> K; else V transposed into Vt[b][e][s].
__global__ __launch_bounds__(256, 3)
void gemm_qkv(const unsigned short* __restrict__ A,
              const unsigned short* __restrict__ Bm,
              unsigned short* __restrict__ Qb,
              unsigned short* __restrict__ Kb,
              unsigned short* __restrict__ Vt)
{
  // T1: bijective XCD swizzle (1536 % 8 == 0). Dispatch order is x-fastest,
  // so lin%8 = XCD id; give each XCD 192 consecutive tiles = 8 full by-rows
  // (A-panel working set 8*256KB = 2MB < 4MB XCD L2).
  const int lin = blockIdx.y * 24 + blockIdx.x;
  const int swz = (lin & 7) * 192 + (lin >> 3);
  const int bx = swz % 24, by = swz / 24;

  __shared__ __align__(16) unsigned short As[128 * BK];  // 16 KB
  __shared__ __align__(16) unsigned short Bs[128 * BK];  // 16 KB

  const int tid = threadIdx.x;
  const int wave = tid >> 6, lane = tid & 63;
  const int wr = wave >> 1, wc = wave & 1;
  const int quad = lane >> 4, l16 = lane & 15;

  const unsigned rsub = wave * 8 + (lane >> 3);
  const unsigned csb = (unsigned)(((lane & 7) ^ ((lane >> 3) & 7)) * 16);  // byte off in row

  // per-lane 32-bit byte offsets; uniform bases stay in SGPRs
  unsigned offA[4], offB[4];
  #pragma unroll
  for (int s = 0; s < 4; ++s) {
    offA[s] = ((unsigned)(by * 128 + s * 32 + rsub) * 1024u) * 2u + csb;
    offB[s] = ((unsigned)(bx * 128 + s * 32 + rsub) * 1024u) * 2u + csb;
  }
  const char* Abase = (const char*)A;
  const char* Bbase = (const char*)Bm;

  f32x4 acc[4][4];
  #pragma unroll
  for (int i = 0; i < 4; ++i)
    #pragma unroll
    for (int j = 0; j < 4; ++j)
      acc[i][j] = (f32x4){0.f, 0.f, 0.f, 0.f};

  const int pq = (quad ^ (l16 & 7)) * 8;
  const int aOff = (wr * 64 + l16) * BK + pq;
  const int bOff = (wc * 64 + l16) * BK + pq;

  for (int k0 = 0; k0 < 1024; k0 += BK) {
    const unsigned kb = (unsigned)k0 * 2u;
    #pragma unroll
    for (int s = 0; s < 4; ++s) {
      gload_lds16(Abase + kb + offA[s], As + s * 2048 + wave * 512);
      gload_lds16(Bbase + kb + offB[s], Bs + s * 2048 + wave * 512);
    }
    __syncthreads();
    #pragma unroll
    for (int h = 0; h < 2; ++h) {
      const int hx = h * 32;
      bf16x8 af[4], bfr[4];
      #pragma unroll
      for (int i = 0; i < 4; ++i)
        af[i] = *(const bf16x8*)(As + ((aOff + i * 16 * BK) ^ hx));
      #pragma unroll
      for (int j = 0; j < 4; ++j)
        bfr[j] = *(const bf16x8*)(Bs + ((bOff + j * 16 * BK) ^ hx));
      #pragma unroll
      for (int i = 0; i < 4; ++i)
        #pragma unroll
        for (int j = 0; j < 4; ++j)
          acc[i][j] = __builtin_amdgcn_mfma_f32_16x16x32_bf16(af[i], bfr[j], acc[i][j], 0, 0, 0);
    }
    __syncthreads();
  }

  const int row0 = by * 128 + wr * 64 + quad * 4;
  const int col0 = bx * 128 + wc * 64 + l16;
  if (bx < 16) {
    unsigned short* C = (bx < 8) ? Qb : Kb;
    const int col = (bx < 8) ? col0 : col0 - 1024;
    #pragma unroll
    for (int i = 0; i < 4; ++i)
      #pragma unroll
      for (int r = 0; r < 4; ++r) {
        const size_t rr = (size_t)(row0 + i * 16 + r) * 1024;
        #pragma unroll
        for (int j = 0; j < 4; ++j)
          C[rr + col + j * 16] = f2bf(acc[i][j][r]);
      }
  } else {
    const int b = row0 >> 11;
    const int s0 = row0 & 2047;
    unsigned short* Vb = Vt + (size_t)b * 2097152;
    #pragma unroll
    for (int j = 0; j < 4; ++j) {
      const size_t ee = (size_t)(col0 - 2048 + j * 16) * 2048;
      #pragma unroll
      for (int i = 0; i < 4; ++i) {
        ushort4 o;
        o.x = f2bf(acc[i][j][0]); o.y = f2bf(acc[i][j][1]);
        o.z = f2bf(acc[i][j][2]); o.w = f2bf(acc[i][j][3]);
        *(ushort4*)(Vb + ee + s0 + i * 16) = o;
      }
    }
  }
}

// -------------------- scores (128x128, BK=64) + exp + rowsum ----------------
// S'[b] = exp(scale*Q@K^T) causal-masked, bf16; L[b][q] += partial rowsums.
// Triangular-packed grid.x (136 tiles), z = batch.
__global__ __launch_bounds__(256, 3)
void gemm_scores(const unsigned short* __restrict__ Q,
                 const unsigned short* __restrict__ Km,
                 unsigned short* __restrict__ S,
                 float* __restrict__ L)
{
  // T1: bijective XCD swizzle over 136 = 8*17 triangular tiles; consecutive
  // t' share by -> Q-panel L2 reuse within an XCD.
  const int t0i = blockIdx.x;
  const int t = (t0i & 7) * 17 + (t0i >> 3);
  const int bz = blockIdx.z;
  int by = (int)((sqrtf(8.f * t + 1.f) - 1.f) * 0.5f);
  while ((by + 1) * (by + 2) / 2 <= t) ++by;
  while (by * (by + 1) / 2 > t) --by;
  const int bx = t - by * (by + 1) / 2;

  __shared__ __align__(16) unsigned short As2[128 * BK];
  __shared__ __align__(16) unsigned short Bs2[128 * BK];

  const int tid = threadIdx.x;
  const int wave = tid >> 6, lane = tid & 63;
  const int wr = wave >> 1, wc = wave & 1;
  const int quad = lane >> 4, l16 = lane & 15;

  const unsigned rsub = wave * 8 + (lane >> 3);
  const unsigned csb = (unsigned)(((lane & 7) ^ ((lane >> 3) & 7)) * 16);

  unsigned offA[4], offB[4];
  #pragma unroll
  for (int s = 0; s < 4; ++s) {
    offA[s] = ((unsigned)(by * 128 + s * 32 + rsub) * 1024u) * 2u + csb;
    offB[s] = ((unsigned)(bx * 128 + s * 32 + rsub) * 1024u) * 2u + csb;
  }
  const char* Abase = (const char*)(Q + (size_t)bz * 2097152);
  const char* Bbase = (const char*)(Km + (size_t)bz * 2097152);

  f32x4 acc[4][4];
  #pragma unroll
  for (int i = 0; i < 4; ++i)
    #pragma unroll
    for (int j = 0; j < 4; ++j)
      acc[i][j] = (f32x4){0.f, 0.f, 0.f, 0.f};

  const int pq = (quad ^ (l16 & 7)) * 8;
  const int aOff = (wr * 64 + l16) * BK + pq;
  const int bOff = (wc * 64 + l16) * BK + pq;

  for (int k0 = 0; k0 < 1024; k0 += BK) {
    const unsigned kb = (unsigned)k0 * 2u;
    #pragma unroll
    for (int s = 0; s < 4; ++s) {
      gload_lds16(Abase + kb + offA[s], As2 + s * 2048 + wave * 512);
      gload_lds16(Bbase + kb + offB[s], Bs2 + s * 2048 + wave * 512);
    }
    __syncthreads();
    #pragma unroll
    for (int h = 0; h < 2; ++h) {
      const int hx = h * 32;
      bf16x8 af[4], bfr[4];
      #pragma unroll
      for (int i = 0; i < 4; ++i)
        af[i] = *(const bf16x8*)(As2 + ((aOff + i * 16 * BK) ^ hx));
      #pragma unroll
      for (int j = 0; j < 4; ++j)
        bfr[j] = *(const bf16x8*)(Bs2 + ((bOff + j * 16 * BK) ^ hx));
      #pragma unroll
      for (int i = 0; i < 4; ++i)
        #pragma unroll
        for (int j = 0; j < 4; ++j)
          acc[i][j] = __builtin_amdgcn_mfma_f32_16x16x32_bf16(af[i], bfr[j], acc[i][j], 0, 0, 0);
    }
    __syncthreads();
  }

  const int row0 = by * 128 + wr * 64 + quad * 4;
  const int col0 = bx * 128 + wc * 64 + l16;
  float* Lb = L + (size_t)bz * 2048;
  unsigned short* C = S + (size_t)bz * 4194304;

  #pragma unroll
  for (int i = 0; i < 4; ++i)
    #pragma unroll
    for (int r = 0; r < 4; ++r) {
      const int grow = row0 + i * 16 + r;
      float ps = 0.f;
      #pragma unroll
      for (int j = 0; j < 4; ++j) {
        const int gcol = col0 + j * 16;
        float e = (gcol <= grow) ? __expf(acc[i][j][r] * 0.03125f) : 0.f;
        acc[i][j][r] = e;
        ps += e;
      }
      #pragma unroll
      for (int m = 8; m > 0; m >>= 1)
        ps += __shfl_xor(ps, m);
      if (l16 == 0) atomicAdd(&Lb[grow], ps);
      const size_t rr = (size_t)grow * 2048;
      #pragma unroll
      for (int j = 0; j < 4; ++j)
        C[rr + col0 + j * 16] = f2bf(acc[i][j][r]);
    }
}

// -------------------- PV (128x128, BK=64) with 1/L normalization ------------
// Out[b] = (P'[b] @ Vt[b]^T) / L; grid 512 linear; kmax = (by+1)*128.
// XCD panel-clustering: HW XCD = lin%8. Decode puts all 8 bx of panel
// r = (lin>>6)*8 + (lin&7) on XCD r%8 (they read the identical P panel ->
// L2 reuse); panels round-robin across XCDs in LPT order (by = 15 - (r>>2),
// bz = r&3): by=15 panels dispatch first, per-XCD k-load 72/64 balanced.
__global__ __launch_bounds__(256, 3)
void gemm_pv(const unsigned short* __restrict__ P,
             const unsigned short* __restrict__ Vt,
             float* __restrict__ Out,
             const float* __restrict__ L)
{
  const int lin = blockIdx.x;                 // 0..511
  const int bx = (lin >> 3) & 7;
  const int r = ((lin >> 6) << 3) | (lin & 7);  // panel rank, XCD = r%8
  const int by = 15 - (r >> 2);
  const int bz = r & 3;

  __shared__ __align__(16) unsigned short As2[128 * BK];
  __shared__ __align__(16) unsigned short Bs2[128 * BK];

  const int tid = threadIdx.x;
  const int wave = tid >> 6, lane = tid & 63;
  const int wr = wave >> 1, wc = wave & 1;
  const int quad = lane >> 4, l16 = lane & 15;

  const unsigned rsub = wave * 8 + (lane >> 3);
  const unsigned csb = (unsigned)(((lane & 7) ^ ((lane >> 3) & 7)) * 16);

  unsigned offA[4], offB[4];
  #pragma unroll
  for (int s = 0; s < 4; ++s) {
    offA[s] = ((unsigned)(by * 128 + s * 32 + rsub) * 2048u) * 2u + csb;
    offB[s] = ((unsigned)(bx * 128 + s * 32 + rsub) * 2048u) * 2u + csb;
  }
  const char* Abase = (const char*)(P + (size_t)bz * 4194304);
  const char* Bbase = (const char*)(Vt + (size_t)bz * 2097152);

  f32x4 acc[4][4];
  #pragma unroll
  for (int i = 0; i < 4; ++i)
    #pragma unroll
    for (int j = 0; j < 4; ++j)
      acc[i][j] = (f32x4){0.f, 0.f, 0.f, 0.f};

  const int kmax = (by + 1) * 128;  // causal truncation, multiple of BK

  const int pq = (quad ^ (l16 & 7)) * 8;
  const int aOff = (wr * 64 + l16) * BK + pq;
  const int bOff = (wc * 64 + l16) * BK + pq;

  for (int k0 = 0; k0 < kmax; k0 += BK) {
    const unsigned kb = (unsigned)k0 * 2u;
    #pragma unroll
    for (int s = 0; s < 4; ++s) {
      gload_lds16(Abase + kb + offA[s], As2 + s * 2048 + wave * 512);
      gload_lds16(Bbase + kb + offB[s], Bs2 + s * 2048 + wave * 512);
    }
    __syncthreads();
    #pragma unroll
    for (int h = 0; h < 2; ++h) {
      const int hx = h * 32;
      bf16x8 af[4], bfr[4];
      #pragma unroll
      for (int i = 0; i < 4; ++i)
        af[i] = *(const bf16x8*)(As2 + ((aOff + i * 16 * BK) ^ hx));
      #pragma unroll
      for (int j = 0; j < 4; ++j)
        bfr[j] = *(const bf16x8*)(Bs2 + ((bOff + j * 16 * BK) ^ hx));
      #pragma unroll
      for (int i = 0; i < 4; ++i)
        #pragma unroll
        for (int j = 0; j < 4; ++j)
          acc[i][j] = __builtin_amdgcn_mfma_f32_16x16x32_bf16(af[i], bfr[j], acc[i][j], 0, 0, 0);
    }
    __syncthreads();
  }

  const int row0 = by * 128 + wr * 64 + quad * 4;
  const int col0 = bx * 128 + wc * 64 + l16;
  float* C = Out + (size_t)bz * 2097152;
  const float* Lb = L + (size_t)bz * 2048;
  #pragma unroll
  for (int i = 0; i < 4; ++i)
    #pragma unroll
    for (int r2 = 0; r2 < 4; ++r2) {
      const int grow = row0 + i * 16 + r2;
      const float inv = 1.0f / Lb[grow];
      const size_t rr = (size_t)grow * 1024;
      #pragma unroll
      for (int j = 0; j < 4; ++j)
        C[rr + col0 + j * 16] = acc[i][j][r2] * inv;
    }
}

// -------------------- launch --------------------
extern "C" void kernel_launch(void* const* d_in, const int* in_sizes, int n_in,
                              void* d_out, int out_size, void* d_ws, size_t ws_size,
                              hipStream_t stream) {
  const float* X  = (const float*)d_in[0];
  const float* Wq = (const float*)d_in[1];
  const float* Wk = (const float*)d_in[2];
  const float* Wv = (const float*)d_in[3];
  float* Out = (float*)d_out;

  char* ws = (char*)d_ws;
  unsigned short* Xbf  = (unsigned short*)(ws);              // [8192][1024]    16 MiB
  unsigned short* Wall = (unsigned short*)(ws + 16777216);   // [3072][1024]     6 MiB
  unsigned short* Qbf  = (unsigned short*)(ws + 23068672);   // [8192][1024]    16 MiB
  unsigned short* Kbf  = (unsigned short*)(ws + 39845888);   // [8192][1024]    16 MiB
  unsigned short* Vt   = (unsigned short*)(ws + 56623104);   // [4][1024][2048] 16 MiB
  unsigned short* Sbf  = (unsigned short*)(ws + 73400320);   // [4][2048][2048] 32 MiB
  float*          Lbuf = (float*)(ws + 106954752);           // [4][2048]       32 KiB

  cvt_all<<<11268, 256, 0, stream>>>(X, Wq, Wk, Wv, Xbf, Wall, Lbuf);

  gemm_qkv<<<dim3(24, 64), 256, 0, stream>>>(Xbf, Wall, Qbf, Kbf, Vt);

  gemm_scores<<<dim3(136, 1, 4), 256, 0, stream>>>(Qbf, Kbf, Sbf, Lbuf);

  gemm_pv<<<512, 256, 0, stream>>>(Sbf, Vt, Out, Lbuf);
}